// Round 3
// baseline (153.678 us; speedup 1.0000x reference)
//
#include <hip/hip_runtime.h>

// SpMM scatter: out[row[e]] += values[e] * x[col[e]],  row sorted.
// Single dispatch. One 64-lane wave per node:
//   - segment bounds via 64-ary p-search (~4 probe rounds) + one-round end scan
//   - edge loop: 4 groups x 16 lanes, float4 gathers, 4x unroll
//     -> up to 16 independent 256B row-gathers in flight per wave
//   - shfl_xor cross-group reduction, lanes 0-15 store the 256B output row

constexpr int D  = 64;
constexpr int DV = D / 4;   // 16 float4 per feature row

__global__ __launch_bounds__(256) void spmm_psearch(
    const int* __restrict__ row,
    const int* __restrict__ col,
    const float* __restrict__ val,
    const float4* __restrict__ x4,
    float4* __restrict__ out4,
    int nEdges, int nNodes)
{
    const int wid = (blockIdx.x * blockDim.x + threadIdx.x) >> 6;   // node id
    if (wid >= nNodes) return;
    const int lane  = threadIdx.x & 63;
    const int group = lane >> 4;    // 0..3 -> edge stripe
    const int sub   = lane & 15;    // 0..15 -> float4 index within row

    // ---- p-ary lower_bound(row, wid): lb in [lo, hi] inclusive ----
    int lo = 0, hi = nEdges;                 // lb may equal nEdges
    const int t0 = wid;
    while (hi > lo) {
        const int span = hi - lo + 1;
        if (span <= 64) {
            const int idx = lo + lane;
            const bool lt = (idx <= hi) && (idx < nEdges) && (row[idx] < t0);
            lo += __popcll(__ballot(lt));
            break;
        }
        const int step = (span + 63) >> 6;   // ceil(span/64) >= 1
        const int idx  = lo + lane * step;
        const bool lt  = (idx <= hi) && (idx < nEdges) && (row[idx] < t0);
        const int  c   = __popcll(__ballot(lt));
        if (c == 0) { hi = lo; break; }      // probe at lo already >= t
        const int new_lo = lo + (c - 1) * step + 1;
        if (c < 64) hi = lo + c * step;      // probe at c*step is >= t
        lo = new_lo;
    }
    const int start = lo;

    // ---- end = lower_bound(row, wid+1), scanning forward from start ----
    const int t1 = wid + 1;
    int end = start;
    for (;;) {
        const int idx = end + lane;
        const bool lt = (idx < nEdges) && (row[idx] < t1);
        const int  c  = __popcll(__ballot(lt));
        end += c;
        if (c < 64) break;                   // degree >= 64 per round: loop (rare)
    }

    // ---- edge loop: stride 16 (4 groups x 4-way unroll) ----
    float4 acc = {0.f, 0.f, 0.f, 0.f};
    for (int e = start + group; e < end; e += 16) {
        const int e1 = e + 4, e2 = e + 8, e3 = e + 12;
        const int   c0 = col[e];
        const float v0 = val[e];
        // invalid slots: gather row c0 again (coalesces onto in-flight lines), weight 0
        int c1 = c0, c2 = c0, c3 = c0;
        float v1 = 0.f, v2 = 0.f, v3 = 0.f;
        if (e1 < end) { c1 = col[e1]; v1 = val[e1]; }
        if (e2 < end) { c2 = col[e2]; v2 = val[e2]; }
        if (e3 < end) { c3 = col[e3]; v3 = val[e3]; }
        const float4 x0 = x4[(size_t)c0 * DV + sub];
        const float4 x1 = x4[(size_t)c1 * DV + sub];
        const float4 x2 = x4[(size_t)c2 * DV + sub];
        const float4 x3 = x4[(size_t)c3 * DV + sub];
        acc.x = fmaf(v0, x0.x, acc.x); acc.y = fmaf(v0, x0.y, acc.y);
        acc.z = fmaf(v0, x0.z, acc.z); acc.w = fmaf(v0, x0.w, acc.w);
        acc.x = fmaf(v1, x1.x, acc.x); acc.y = fmaf(v1, x1.y, acc.y);
        acc.z = fmaf(v1, x1.z, acc.z); acc.w = fmaf(v1, x1.w, acc.w);
        acc.x = fmaf(v2, x2.x, acc.x); acc.y = fmaf(v2, x2.y, acc.y);
        acc.z = fmaf(v2, x2.z, acc.z); acc.w = fmaf(v2, x2.w, acc.w);
        acc.x = fmaf(v3, x3.x, acc.x); acc.y = fmaf(v3, x3.y, acc.y);
        acc.z = fmaf(v3, x3.z, acc.z); acc.w = fmaf(v3, x3.w, acc.w);
    }

    // ---- reduce partials across the 4 groups (lanes ^16, ^32) ----
    #pragma unroll
    for (int off = 16; off <= 32; off <<= 1) {
        acc.x += __shfl_xor(acc.x, off, 64);
        acc.y += __shfl_xor(acc.y, off, 64);
        acc.z += __shfl_xor(acc.z, off, 64);
        acc.w += __shfl_xor(acc.w, off, 64);
    }
    if (group == 0) out4[(size_t)wid * DV + sub] = acc;   // 256B coalesced store
}

extern "C" void kernel_launch(void* const* d_in, const int* in_sizes, int n_in,
                              void* d_out, int out_size, void* d_ws, size_t ws_size,
                              hipStream_t stream)
{
    const int*    row  = (const int*)   d_in[0];
    const int*    col  = (const int*)   d_in[1];
    const float*  val  = (const float*) d_in[2];
    const float4* x4   = (const float4*)d_in[3];
    float4*       out4 = (float4*)d_out;

    const int nEdges = in_sizes[0];
    const int nNodes = out_size / D;            // 100000

    const dim3 block(256);
    const dim3 grid(((size_t)nNodes * 64 + 255) / 256);
    spmm_psearch<<<grid, block, 0, stream>>>(row, col, val, x4, out4, nEdges, nNodes);
}

// Round 4
// 135.352 us; speedup vs baseline: 1.1354x; 1.1354x over previous
//
#include <hip/hip_runtime.h>
#include <hip/hip_fp16.h>

// SpMM scatter: out[row[e]] += values[e] * x[col[e]],  row sorted, D=64.
// Bottleneck model: scattered L2 cache-line requests from gathering x rows.
//   fp32 row = 256B = 4 lines/edge -> fp16 row = 128B = 2 lines/edge.
// Dispatch 1 (prep): fused  (a) x fp32 -> fp16 into d_ws  (b) row_ptr build.
//   Both are 1.6M-thread coalesced edge/chunk-parallel jobs -> one kernel.
// Dispatch 2 (main): one 64-lane wave per node, 4 groups x 16 lanes,
//   8B fp16 gathers, 4x unroll (16 gathers in flight), shfl_xor reduction,
//   fp32 accumulate, 256B coalesced store.

constexpr int D  = 64;
constexpr int DV = 16;   // float4 chunks per output row
constexpr int DH = 16;   // 8B fp16x4 chunks per x row

struct __align__(8) h4 { __half2 a, b; };

__global__ __launch_bounds__(256) void prep_kernel(
    const int* __restrict__ row,
    const float4* __restrict__ x4,
    h4* __restrict__ xh,
    int* __restrict__ row_ptr,
    int nEdges, int n4, int nNodes)
{
    const int i = blockIdx.x * blockDim.x + threadIdx.x;
    if (i < n4) {                       // fp32 -> fp16 convert (coalesced)
        const float4 v = x4[i];
        h4 h;
        h.a = __float22half2_rn(make_float2(v.x, v.y));
        h.b = __float22half2_rn(make_float2(v.z, v.w));
        xh[i] = h;
    }
    if (i < nEdges) {                   // row_ptr build (R2-proven)
        const int r    = row[i];
        const int prev = (i == 0) ? -1 : row[i - 1];
        for (int n = prev + 1; n <= r; ++n) row_ptr[n] = i;
        if (i == nEdges - 1)
            for (int n = r + 1; n <= nNodes; ++n) row_ptr[n] = nEdges;
    }
}

__global__ __launch_bounds__(256) void spmm_h(
    const int* __restrict__ row_ptr,
    const int* __restrict__ col,
    const float* __restrict__ val,
    const h4* __restrict__ xh,
    float4* __restrict__ out4,
    int nNodes)
{
    const int wid = (blockIdx.x * blockDim.x + threadIdx.x) >> 6;   // node id
    if (wid >= nNodes) return;
    const int lane  = threadIdx.x & 63;
    const int group = lane >> 4;    // 0..3 -> edge stripe
    const int sub   = lane & 15;    // 0..15 -> 8B chunk within row

    const int start = row_ptr[wid];
    const int end   = row_ptr[wid + 1];

    float4 acc = {0.f, 0.f, 0.f, 0.f};
    for (int e = start + group; e < end; e += 16) {
        const int e1 = e + 4, e2 = e + 8, e3 = e + 12;
        const int   c0 = col[e];
        const float v0 = val[e];
        // dummy slots re-gather row c0 (lines already in flight), weight 0
        int c1 = c0, c2 = c0, c3 = c0;
        float v1 = 0.f, v2 = 0.f, v3 = 0.f;
        if (e1 < end) { c1 = col[e1]; v1 = val[e1]; }
        if (e2 < end) { c2 = col[e2]; v2 = val[e2]; }
        if (e3 < end) { c3 = col[e3]; v3 = val[e3]; }
        const h4 p0 = xh[(size_t)c0 * DH + sub];
        const h4 p1 = xh[(size_t)c1 * DH + sub];
        const h4 p2 = xh[(size_t)c2 * DH + sub];
        const h4 p3 = xh[(size_t)c3 * DH + sub];
        float2 f;
        f = __half22float2(p0.a); acc.x = fmaf(v0, f.x, acc.x); acc.y = fmaf(v0, f.y, acc.y);
        f = __half22float2(p0.b); acc.z = fmaf(v0, f.x, acc.z); acc.w = fmaf(v0, f.y, acc.w);
        f = __half22float2(p1.a); acc.x = fmaf(v1, f.x, acc.x); acc.y = fmaf(v1, f.y, acc.y);
        f = __half22float2(p1.b); acc.z = fmaf(v1, f.x, acc.z); acc.w = fmaf(v1, f.y, acc.w);
        f = __half22float2(p2.a); acc.x = fmaf(v2, f.x, acc.x); acc.y = fmaf(v2, f.y, acc.y);
        f = __half22float2(p2.b); acc.z = fmaf(v2, f.x, acc.z); acc.w = fmaf(v2, f.y, acc.w);
        f = __half22float2(p3.a); acc.x = fmaf(v3, f.x, acc.x); acc.y = fmaf(v3, f.y, acc.y);
        f = __half22float2(p3.b); acc.z = fmaf(v3, f.x, acc.z); acc.w = fmaf(v3, f.y, acc.w);
    }

    #pragma unroll
    for (int off = 16; off <= 32; off <<= 1) {
        acc.x += __shfl_xor(acc.x, off, 64);
        acc.y += __shfl_xor(acc.y, off, 64);
        acc.z += __shfl_xor(acc.z, off, 64);
        acc.w += __shfl_xor(acc.w, off, 64);
    }
    if (group == 0) out4[(size_t)wid * DV + sub] = acc;   // 256B coalesced store
}

// Fallback (ws too small): R3's single-dispatch p-search kernel, fp32 (proven).
__global__ __launch_bounds__(256) void spmm_psearch(
    const int* __restrict__ row,
    const int* __restrict__ col,
    const float* __restrict__ val,
    const float4* __restrict__ x4,
    float4* __restrict__ out4,
    int nEdges, int nNodes)
{
    const int wid = (blockIdx.x * blockDim.x + threadIdx.x) >> 6;
    if (wid >= nNodes) return;
    const int lane  = threadIdx.x & 63;
    const int group = lane >> 4;
    const int sub   = lane & 15;

    int lo = 0, hi = nEdges;
    const int t0 = wid;
    while (hi > lo) {
        const int span = hi - lo + 1;
        if (span <= 64) {
            const int idx = lo + lane;
            const bool lt = (idx <= hi) && (idx < nEdges) && (row[idx] < t0);
            lo += __popcll(__ballot(lt));
            break;
        }
        const int step = (span + 63) >> 6;
        const int idx  = lo + lane * step;
        const bool lt  = (idx <= hi) && (idx < nEdges) && (row[idx] < t0);
        const int  c   = __popcll(__ballot(lt));
        if (c == 0) { hi = lo; break; }
        const int new_lo = lo + (c - 1) * step + 1;
        if (c < 64) hi = lo + c * step;
        lo = new_lo;
    }
    const int start = lo;
    const int t1 = wid + 1;
    int end = start;
    for (;;) {
        const int idx = end + lane;
        const bool lt = (idx < nEdges) && (row[idx] < t1);
        const int  c  = __popcll(__ballot(lt));
        end += c;
        if (c < 64) break;
    }

    float4 acc = {0.f, 0.f, 0.f, 0.f};
    for (int e = start + group; e < end; e += 8) {
        const int e1 = e + 4;
        const int   c0 = col[e];
        const float v0 = val[e];
        int c1 = c0; float v1 = 0.f;
        if (e1 < end) { c1 = col[e1]; v1 = val[e1]; }
        const float4 x0 = x4[(size_t)c0 * DV + sub];
        const float4 x1 = x4[(size_t)c1 * DV + sub];
        acc.x = fmaf(v0, x0.x, acc.x); acc.y = fmaf(v0, x0.y, acc.y);
        acc.z = fmaf(v0, x0.z, acc.z); acc.w = fmaf(v0, x0.w, acc.w);
        acc.x = fmaf(v1, x1.x, acc.x); acc.y = fmaf(v1, x1.y, acc.y);
        acc.z = fmaf(v1, x1.z, acc.z); acc.w = fmaf(v1, x1.w, acc.w);
    }
    #pragma unroll
    for (int off = 16; off <= 32; off <<= 1) {
        acc.x += __shfl_xor(acc.x, off, 64);
        acc.y += __shfl_xor(acc.y, off, 64);
        acc.z += __shfl_xor(acc.z, off, 64);
        acc.w += __shfl_xor(acc.w, off, 64);
    }
    if (group == 0) out4[(size_t)wid * DV + sub] = acc;
}

extern "C" void kernel_launch(void* const* d_in, const int* in_sizes, int n_in,
                              void* d_out, int out_size, void* d_ws, size_t ws_size,
                              hipStream_t stream)
{
    const int*    row  = (const int*)   d_in[0];
    const int*    col  = (const int*)   d_in[1];
    const float*  val  = (const float*) d_in[2];
    const float4* x4   = (const float4*)d_in[3];
    float4*       out4 = (float4*)d_out;

    const int nEdges = in_sizes[0];
    const int nNodes = out_size / D;            // 100000
    const int n4     = nNodes * DV;             // 1.6M fp16x4 chunks

    const dim3 block(256);
    const dim3 gridMain(((size_t)nNodes * 64 + 255) / 256);

    const size_t rp_bytes = (size_t)(nNodes + 1) * sizeof(int);
    const size_t xh_off   = (rp_bytes + 255) & ~(size_t)255;
    const size_t need     = xh_off + (size_t)nNodes * D * sizeof(__half);

    if (ws_size >= need) {
        int* row_ptr = (int*)d_ws;
        h4*  xh      = (h4*)((char*)d_ws + xh_off);
        const int prep_n = (nEdges > n4) ? nEdges : n4;
        prep_kernel<<<dim3((prep_n + 255) / 256), block, 0, stream>>>(
            row, x4, xh, row_ptr, nEdges, n4, nNodes);
        spmm_h<<<gridMain, block, 0, stream>>>(
            row_ptr, (const int*)d_in[1], val, xh, out4, nNodes);
    } else {
        spmm_psearch<<<gridMain, block, 0, stream>>>(
            row, (const int*)d_in[1], val, x4, out4, nEdges, nNodes);
    }
}

// Round 5
// 124.478 us; speedup vs baseline: 1.2346x; 1.0874x over previous
//
#include <hip/hip_runtime.h>
#include <hip/hip_fp16.h>

// SpMM scatter: out[row[e]] += values[e] * x[col[e]],  row sorted, D=64.
// Bottleneck model (fits R1/R2/R4): VMEM-instruction issue rate (~16 cyc/wave
// vector-mem instr in the TA), NOT bytes. So: minimize VMEM instrs per edge.
//   - col/val: preloaded ONCE per wave (lane i -> edge start+i), shfl-distributed
//   - gathers: 8 groups x 8 lanes x 16B (h8) -> 1 instr covers 8 edge-rows
//   - row_ptr: readfirstlane -> s_load (scalar cache, zero TA)
// Dispatch 1 (prep): x fp32->fp16 (h8 chunks) + row_ptr build, fused.
// Dispatch 2 (main): one wave per node, fp32 accumulate, shfl_xor reduce, store.

constexpr int D   = 64;
constexpr int DV  = 16;  // float4 chunks per out row
constexpr int DH8 = 8;   // 16B h8 chunks per fp16 x row (128B)

struct __align__(16) h8 { __half2 a, b, c, d; };

__global__ __launch_bounds__(256) void prep_kernel(
    const int* __restrict__ row,
    const float4* __restrict__ x4,
    h8* __restrict__ xh,
    int* __restrict__ row_ptr,
    int nEdges, int n8, int nNodes)
{
    const int i = blockIdx.x * blockDim.x + threadIdx.x;
    if (i < n8) {                       // fp32 -> fp16, 32B in / 16B out per thread
        const float4 lo = x4[2 * i];
        const float4 hi = x4[2 * i + 1];
        h8 h;
        h.a = __float22half2_rn(make_float2(lo.x, lo.y));
        h.b = __float22half2_rn(make_float2(lo.z, lo.w));
        h.c = __float22half2_rn(make_float2(hi.x, hi.y));
        h.d = __float22half2_rn(make_float2(hi.z, hi.w));
        xh[i] = h;
    }
    if (i < nEdges) {                   // row_ptr build (R2-proven)
        const int r    = row[i];
        const int prev = (i == 0) ? -1 : row[i - 1];
        for (int n = prev + 1; n <= r; ++n) row_ptr[n] = i;
        if (i == nEdges - 1)
            for (int n = r + 1; n <= nNodes; ++n) row_ptr[n] = nEdges;
    }
}

__device__ __forceinline__ void fma_h8(const h8& p, float v, float4& a0, float4& a1)
{
    float2 f;
    f = __half22float2(p.a); a0.x = fmaf(v, f.x, a0.x); a0.y = fmaf(v, f.y, a0.y);
    f = __half22float2(p.b); a0.z = fmaf(v, f.x, a0.z); a0.w = fmaf(v, f.y, a0.w);
    f = __half22float2(p.c); a1.x = fmaf(v, f.x, a1.x); a1.y = fmaf(v, f.y, a1.y);
    f = __half22float2(p.d); a1.z = fmaf(v, f.x, a1.z); a1.w = fmaf(v, f.y, a1.w);
}

__global__ __launch_bounds__(256) void spmm_h8(
    const int* __restrict__ row_ptr,
    const int* __restrict__ col,
    const float* __restrict__ val,
    const h8* __restrict__ xh,
    float4* __restrict__ out4,
    int nNodes)
{
    const int wid = (blockIdx.x * blockDim.x + threadIdx.x) >> 6;   // node id
    if (wid >= nNodes) return;
    const int lane = threadIdx.x & 63;
    const int g    = lane >> 3;     // 0..7 -> edge slot pair
    const int sub  = lane & 7;      // 16B chunk within x row

    const int uw    = __builtin_amdgcn_readfirstlane(wid);
    const int start = row_ptr[uw];        // s_load (uniform addr)
    const int end   = row_ptr[uw + 1];    // s_load
    const int deg   = end - start;

    // preload up to 64 edges' col/val: 2 VMEM instrs for the whole wave
    const int  eL  = start + lane;
    const bool okL = eL < end;
    const int   cv = okL ? col[eL] : 0;
    const float vv = okL ? val[eL] : 0.f;   // invalid slots weight 0

    float4 a0 = {0.f, 0.f, 0.f, 0.f};
    float4 a1 = {0.f, 0.f, 0.f, 0.f};

    // 16 edges per iteration: group g handles slots 2g, 2g+1
    const int it64 = min((deg + 15) >> 4, 4);
    for (int it = 0; it < it64; ++it) {
        const int s0 = it * 16 + 2 * g;
        const int   c0 = __shfl(cv, s0, 64);
        const float v0 = __shfl(vv, s0, 64);
        const int   c1 = __shfl(cv, s0 + 1, 64);
        const float v1 = __shfl(vv, s0 + 1, 64);
        const h8 p0 = xh[(size_t)c0 * DH8 + sub];   // 1 instr = 8 rows (1KB)
        const h8 p1 = xh[(size_t)c1 * DH8 + sub];
        fma_h8(p0, v0, a0, a1);
        fma_h8(p1, v1, a0, a1);
    }

    // rare remainder (deg > 64): direct loads
    for (int ebase = start + 64; ebase < end; ebase += 16) {
        const int e0 = ebase + 2 * g, e1 = e0 + 1;
        int c0 = 0, c1 = 0; float v0 = 0.f, v1 = 0.f;
        if (e0 < end) { c0 = col[e0]; v0 = val[e0]; }
        if (e1 < end) { c1 = col[e1]; v1 = val[e1]; }
        const h8 p0 = xh[(size_t)c0 * DH8 + sub];
        const h8 p1 = xh[(size_t)c1 * DH8 + sub];
        fma_h8(p0, v0, a0, a1);
        fma_h8(p1, v1, a0, a1);
    }

    // reduce across the 8 groups (lanes ^8, ^16, ^32)
    #pragma unroll
    for (int off = 8; off <= 32; off <<= 1) {
        a0.x += __shfl_xor(a0.x, off, 64); a0.y += __shfl_xor(a0.y, off, 64);
        a0.z += __shfl_xor(a0.z, off, 64); a0.w += __shfl_xor(a0.w, off, 64);
        a1.x += __shfl_xor(a1.x, off, 64); a1.y += __shfl_xor(a1.y, off, 64);
        a1.z += __shfl_xor(a1.z, off, 64); a1.w += __shfl_xor(a1.w, off, 64);
    }
    if (g == 0) {   // lanes 0..7 hold the row; lane sub owns features [8sub, 8sub+8)
        out4[(size_t)wid * DV + 2 * sub]     = a0;
        out4[(size_t)wid * DV + 2 * sub + 1] = a1;
    }
}

// Fallback (ws too small): single-dispatch p-search kernel, fp32 (R3-proven).
__global__ __launch_bounds__(256) void spmm_psearch(
    const int* __restrict__ row,
    const int* __restrict__ col,
    const float* __restrict__ val,
    const float4* __restrict__ x4,
    float4* __restrict__ out4,
    int nEdges, int nNodes)
{
    const int wid = (blockIdx.x * blockDim.x + threadIdx.x) >> 6;
    if (wid >= nNodes) return;
    const int lane  = threadIdx.x & 63;
    const int group = lane >> 4;
    const int sub   = lane & 15;

    int lo = 0, hi = nEdges;
    const int t0 = wid;
    while (hi > lo) {
        const int span = hi - lo + 1;
        if (span <= 64) {
            const int idx = lo + lane;
            const bool lt = (idx <= hi) && (idx < nEdges) && (row[idx] < t0);
            lo += __popcll(__ballot(lt));
            break;
        }
        const int step = (span + 63) >> 6;
        const int idx  = lo + lane * step;
        const bool lt  = (idx <= hi) && (idx < nEdges) && (row[idx] < t0);
        const int  c   = __popcll(__ballot(lt));
        if (c == 0) { hi = lo; break; }
        const int new_lo = lo + (c - 1) * step + 1;
        if (c < 64) hi = lo + c * step;
        lo = new_lo;
    }
    const int start = lo;
    const int t1 = wid + 1;
    int end = start;
    for (;;) {
        const int idx = end + lane;
        const bool lt = (idx < nEdges) && (row[idx] < t1);
        const int  c  = __popcll(__ballot(lt));
        end += c;
        if (c < 64) break;
    }

    float4 acc = {0.f, 0.f, 0.f, 0.f};
    for (int e = start + group; e < end; e += 8) {
        const int e1 = e + 4;
        const int   c0 = col[e];
        const float v0 = val[e];
        int c1 = c0; float v1 = 0.f;
        if (e1 < end) { c1 = col[e1]; v1 = val[e1]; }
        const float4 x0 = x4[(size_t)c0 * DV + sub];
        const float4 x1 = x4[(size_t)c1 * DV + sub];
        acc.x = fmaf(v0, x0.x, acc.x); acc.y = fmaf(v0, x0.y, acc.y);
        acc.z = fmaf(v0, x0.z, acc.z); acc.w = fmaf(v0, x0.w, acc.w);
        acc.x = fmaf(v1, x1.x, acc.x); acc.y = fmaf(v1, x1.y, acc.y);
        acc.z = fmaf(v1, x1.z, acc.z); acc.w = fmaf(v1, x1.w, acc.w);
    }
    #pragma unroll
    for (int off = 16; off <= 32; off <<= 1) {
        acc.x += __shfl_xor(acc.x, off, 64);
        acc.y += __shfl_xor(acc.y, off, 64);
        acc.z += __shfl_xor(acc.z, off, 64);
        acc.w += __shfl_xor(acc.w, off, 64);
    }
    if (group == 0) out4[(size_t)wid * DV + sub] = acc;
}

extern "C" void kernel_launch(void* const* d_in, const int* in_sizes, int n_in,
                              void* d_out, int out_size, void* d_ws, size_t ws_size,
                              hipStream_t stream)
{
    const int*    row  = (const int*)   d_in[0];
    const int*    col  = (const int*)   d_in[1];
    const float*  val  = (const float*) d_in[2];
    const float4* x4   = (const float4*)d_in[3];
    float4*       out4 = (float4*)d_out;

    const int nEdges = in_sizes[0];
    const int nNodes = out_size / D;            // 100000
    const int n8     = nNodes * DH8;            // 800k h8 chunks

    const dim3 block(256);
    const dim3 gridMain(((size_t)nNodes * 64 + 255) / 256);

    const size_t rp_bytes = (size_t)(nNodes + 1) * sizeof(int);
    const size_t xh_off   = (rp_bytes + 255) & ~(size_t)255;
    const size_t need     = xh_off + (size_t)nNodes * D * sizeof(__half);

    if (ws_size >= need) {
        int* row_ptr = (int*)d_ws;
        h8*  xh      = (h8*)((char*)d_ws + xh_off);
        const int prep_n = (nEdges > n8) ? nEdges : n8;
        prep_kernel<<<dim3((prep_n + 255) / 256), block, 0, stream>>>(
            row, x4, xh, row_ptr, nEdges, n8, nNodes);
        spmm_h8<<<gridMain, block, 0, stream>>>(
            row_ptr, col, val, xh, out4, nNodes);
    } else {
        spmm_psearch<<<gridMain, block, 0, stream>>>(
            row, col, val, x4, out4, nEdges, nNodes);
    }
}

// Round 6
// 123.359 us; speedup vs baseline: 1.2458x; 1.0091x over previous
//
#include <hip/hip_runtime.h>
#include <hip/hip_fp16.h>

// SpMM scatter: out[row[e]] += values[e] * x[col[e]],  row sorted, D=64.
// Bottleneck: VMEM-instruction issue rate (TA), not bytes. Minimize VMEM/node.
// R6: TWO nodes per 64-lane wave (pair edge range is contiguous, avg 32 <= 64):
//   - one col/val preload pair serves both nodes        (2 VMEM / 2 nodes)
//   - 8B-row fp16 gathers: 8 groups x 8 lanes x 16B     (8 edge-rows / instr)
//   - shfl repack -> ONE store instr for both 256B rows (1 VMEM / 2 nodes)
//   - row_ptr via uniform s_loads (scalar cache, no TA)
// Dispatch 1 (prep): x fp32->fp16 (h8) + row_ptr build, fused (R5-proven).

constexpr int D   = 64;
constexpr int DV  = 16;  // float4 chunks per out row
constexpr int DH8 = 8;   // 16B h8 chunks per fp16 x row (128B)

struct __align__(16) h8 { __half2 a, b, c, d; };

__global__ __launch_bounds__(256) void prep_kernel(
    const int* __restrict__ row,
    const float4* __restrict__ x4,
    h8* __restrict__ xh,
    int* __restrict__ row_ptr,
    int nEdges, int n8, int nNodes)
{
    const int i = blockIdx.x * blockDim.x + threadIdx.x;
    if (i < n8) {                       // fp32 -> fp16, 32B in / 16B out
        const float4 lo = x4[2 * i];
        const float4 hi = x4[2 * i + 1];
        h8 h;
        h.a = __float22half2_rn(make_float2(lo.x, lo.y));
        h.b = __float22half2_rn(make_float2(lo.z, lo.w));
        h.c = __float22half2_rn(make_float2(hi.x, hi.y));
        h.d = __float22half2_rn(make_float2(hi.z, hi.w));
        xh[i] = h;
    }
    if (i < nEdges) {                   // row_ptr build (R2-proven)
        const int r    = row[i];
        const int prev = (i == 0) ? -1 : row[i - 1];
        for (int n = prev + 1; n <= r; ++n) row_ptr[n] = i;
        if (i == nEdges - 1)
            for (int n = r + 1; n <= nNodes; ++n) row_ptr[n] = nEdges;
    }
}

__device__ __forceinline__ void fma_h8(const h8& p, float v, float4& a0, float4& a1)
{
    float2 f;
    f = __half22float2(p.a); a0.x = fmaf(v, f.x, a0.x); a0.y = fmaf(v, f.y, a0.y);
    f = __half22float2(p.b); a0.z = fmaf(v, f.x, a0.z); a0.w = fmaf(v, f.y, a0.w);
    f = __half22float2(p.c); a1.x = fmaf(v, f.x, a1.x); a1.y = fmaf(v, f.y, a1.y);
    f = __half22float2(p.d); a1.z = fmaf(v, f.x, a1.z); a1.w = fmaf(v, f.y, a1.w);
}

__global__ __launch_bounds__(256) void spmm_h8x2(
    const int* __restrict__ row_ptr,
    const int* __restrict__ col,
    const float* __restrict__ val,
    const h8* __restrict__ xh,
    float4* __restrict__ out4,
    int nPairs, int nNodes)
{
    const int pw = (blockIdx.x * blockDim.x + threadIdx.x) >> 6;   // node pair id
    if (pw >= nPairs) return;
    const int lane = threadIdx.x & 63;
    const int half = lane >> 5;        // 0/1 -> node 2*pw+half
    const int g    = (lane >> 3) & 3;  // group within half (4 groups x 8 lanes)
    const int sub  = lane & 7;         // 16B h8 chunk within x row

    const int upw = __builtin_amdgcn_readfirstlane(pw);
    const int n0  = upw * 2;
    const bool has1 = (n0 + 1) < nNodes;

    const int s0 = row_ptr[n0];                       // uniform -> s_load
    const int s1 = row_ptr[n0 + 1];
    const int s2 = has1 ? row_ptr[n0 + 2] : s1;
    const int d0 = s1 - s0;                           // deg of node0
    const int d1 = s2 - s1;                           // deg of node1
    const int span = s2 - s0;

    float4 a0 = {0.f, 0.f, 0.f, 0.f};
    float4 a1 = {0.f, 0.f, 0.f, 0.f};

    if (span <= 64) {
        // one preload pair serves both nodes: 2 VMEM for the wave
        const int  eL  = s0 + lane;
        const bool okL = eL < s2;
        const int   cv = okL ? col[eL] : 0;
        const float vv = okL ? val[eL] : 0.f;

        const int bh    = half ? d0 : 0;              // this half's slot base
        const int degh  = half ? d1 : d0;
        const int itmax = (max(d0, d1) + 3) >> 2;     // uniform loop count
        for (int it = 0; it < itmax; ++it) {
            const int  sl   = it * 4 + g;             // local edge index
            const bool ok   = sl < degh;
            const int  slot = min(bh + (ok ? sl : 0), 63);
            const int   c = __shfl(cv, slot, 64);     // col (or safe dummy 0)
            float       v = __shfl(vv, slot, 64);
            v = ok ? v : 0.f;
            const h8 p = xh[(size_t)c * DH8 + sub];   // 1 instr = 8 edge-rows
            fma_h8(p, v, a0, a1);
        }
    } else {
        // rare: pair spans >64 edges -> direct loads, 4 edges/iter per half
        const int bs = half ? s1 : s0;
        const int be = half ? s2 : s1;
        for (int e = bs + g; e < be; e += 4) {
            const int   c = col[e];                   // 8-lane broadcast load
            const float v = val[e];
            const h8 p = xh[(size_t)c * DH8 + sub];
            fma_h8(p, v, a0, a1);
        }
    }

    // reduce across the 4 groups within each 32-lane half (lanes ^8, ^16)
    #pragma unroll
    for (int off = 8; off <= 16; off <<= 1) {
        a0.x += __shfl_xor(a0.x, off, 64); a0.y += __shfl_xor(a0.y, off, 64);
        a0.z += __shfl_xor(a0.z, off, 64); a0.w += __shfl_xor(a0.w, off, 64);
        a1.x += __shfl_xor(a1.x, off, 64); a1.y += __shfl_xor(a1.y, off, 64);
        a1.z += __shfl_xor(a1.z, off, 64); a1.w += __shfl_xor(a1.w, off, 64);
    }

    // repack: lane 32h+s holds float4 chunks (2s,2s+1); move to lanes 32h+t,
    // t=0..15 each holding chunk t -> ONE wave-wide dwordx4 store, both rows.
    const int t   = lane & 31;
    const int src = (lane & 32) + (t >> 1);
    float4 b0, b1;
    b0.x = __shfl(a0.x, src, 64); b0.y = __shfl(a0.y, src, 64);
    b0.z = __shfl(a0.z, src, 64); b0.w = __shfl(a0.w, src, 64);
    b1.x = __shfl(a1.x, src, 64); b1.y = __shfl(a1.y, src, 64);
    b1.z = __shfl(a1.z, src, 64); b1.w = __shfl(a1.w, src, 64);
    const float4 r = (t & 1) ? b1 : b0;
    const int node = n0 + half;
    if (t < 16 && node < nNodes)
        out4[(size_t)node * DV + t] = r;
}

// Fallback (ws too small): single-dispatch p-search kernel, fp32 (R3-proven).
__global__ __launch_bounds__(256) void spmm_psearch(
    const int* __restrict__ row,
    const int* __restrict__ col,
    const float* __restrict__ val,
    const float4* __restrict__ x4,
    float4* __restrict__ out4,
    int nEdges, int nNodes)
{
    const int wid = (blockIdx.x * blockDim.x + threadIdx.x) >> 6;
    if (wid >= nNodes) return;
    const int lane  = threadIdx.x & 63;
    const int group = lane >> 4;
    const int sub   = lane & 15;

    int lo = 0, hi = nEdges;
    const int t0 = wid;
    while (hi > lo) {
        const int span = hi - lo + 1;
        if (span <= 64) {
            const int idx = lo + lane;
            const bool lt = (idx <= hi) && (idx < nEdges) && (row[idx] < t0);
            lo += __popcll(__ballot(lt));
            break;
        }
        const int step = (span + 63) >> 6;
        const int idx  = lo + lane * step;
        const bool lt  = (idx <= hi) && (idx < nEdges) && (row[idx] < t0);
        const int  c   = __popcll(__ballot(lt));
        if (c == 0) { hi = lo; break; }
        const int new_lo = lo + (c - 1) * step + 1;
        if (c < 64) hi = lo + c * step;
        lo = new_lo;
    }
    const int start = lo;
    const int t1 = wid + 1;
    int end = start;
    for (;;) {
        const int idx = end + lane;
        const bool lt = (idx < nEdges) && (row[idx] < t1);
        const int  c  = __popcll(__ballot(lt));
        end += c;
        if (c < 64) break;
    }

    float4 acc = {0.f, 0.f, 0.f, 0.f};
    for (int e = start + group; e < end; e += 8) {
        const int e1 = e + 4;
        const int   c0 = col[e];
        const float v0 = val[e];
        int c1 = c0; float v1 = 0.f;
        if (e1 < end) { c1 = col[e1]; v1 = val[e1]; }
        const float4 x0 = x4[(size_t)c0 * DV + sub];
        const float4 x1 = x4[(size_t)c1 * DV + sub];
        acc.x = fmaf(v0, x0.x, acc.x); acc.y = fmaf(v0, x0.y, acc.y);
        acc.z = fmaf(v0, x0.z, acc.z); acc.w = fmaf(v0, x0.w, acc.w);
        acc.x = fmaf(v1, x1.x, acc.x); acc.y = fmaf(v1, x1.y, acc.y);
        acc.z = fmaf(v1, x1.z, acc.z); acc.w = fmaf(v1, x1.w, acc.w);
    }
    #pragma unroll
    for (int off = 16; off <= 32; off <<= 1) {
        acc.x += __shfl_xor(acc.x, off, 64);
        acc.y += __shfl_xor(acc.y, off, 64);
        acc.z += __shfl_xor(acc.z, off, 64);
        acc.w += __shfl_xor(acc.w, off, 64);
    }
    if (group == 0) out4[(size_t)wid * DV + sub] = acc;
}

extern "C" void kernel_launch(void* const* d_in, const int* in_sizes, int n_in,
                              void* d_out, int out_size, void* d_ws, size_t ws_size,
                              hipStream_t stream)
{
    const int*    row  = (const int*)   d_in[0];
    const int*    col  = (const int*)   d_in[1];
    const float*  val  = (const float*) d_in[2];
    const float4* x4   = (const float4*)d_in[3];
    float4*       out4 = (float4*)d_out;

    const int nEdges = in_sizes[0];
    const int nNodes = out_size / D;            // 100000
    const int n8     = nNodes * DH8;            // 800k h8 chunks
    const int nPairs = (nNodes + 1) / 2;        // 50000

    const dim3 block(256);

    const size_t rp_bytes = (size_t)(nNodes + 1) * sizeof(int);
    const size_t xh_off   = (rp_bytes + 255) & ~(size_t)255;
    const size_t need     = xh_off + (size_t)nNodes * D * sizeof(__half);

    if (ws_size >= need) {
        int* row_ptr = (int*)d_ws;
        h8*  xh      = (h8*)((char*)d_ws + xh_off);
        const int prep_n = (nEdges > n8) ? nEdges : n8;
        prep_kernel<<<dim3((prep_n + 255) / 256), block, 0, stream>>>(
            row, x4, xh, row_ptr, nEdges, n8, nNodes);
        spmm_h8x2<<<dim3(((size_t)nPairs * 64 + 255) / 256), block, 0, stream>>>(
            row_ptr, col, val, xh, out4, nPairs, nNodes);
    } else {
        spmm_psearch<<<dim3(((size_t)nNodes * 64 + 255) / 256), block, 0, stream>>>(
            row, col, val, x4, out4, nEdges, nNodes);
    }
}